// Round 5
// baseline (737.685 us; speedup 1.0000x reference)
//
#include <hip/hip_runtime.h>
#include <hip/hip_bf16.h>

// GCN: 3 x [ relu(A @ (X @ W) + b) ]  (no relu layer 3), fp32 I/O, bf16 MFMA.
// PERSISTENT mega-kernel: 256 blocks (1/CU, co-resident), runs all 6 GEMMs.
//   G1: T  = W^T @ X^T : core(A=WT [F][F], BT=X [N][F]) -> PT [F][N]
//   G2: X' = adj @ T^T : core(A=adjb [N][N], BT=PT)     -> X' [N][F]
// G1->G2 edge: per-tile release/acquire flags (G2 K-tile kt needs G1 node-tile
// kt>>2 only) -> G2 overlaps G1's tail. adj f32->bf16 cvt folded into G1_1
// phase (per-batch counters). G2->next-G1 edge: software grid barrier (WAR on
// PT). Sync state zeroed by a pre-kernel every launch (replay-safe).
// Core GEMM: 256x256 tile, BK=64, 8 waves (2Mx4N), dbuf LDS, read-ahead
// 4-phase pipeline, XOR-swizzled LDS, setprio, XCD-chunked block swizzle,
// LDS-bounced us8 coalesced epilogue.

typedef __attribute__((ext_vector_type(8))) short bf16x8s;
typedef __attribute__((ext_vector_type(4))) float f32x4;
typedef __attribute__((ext_vector_type(4))) unsigned short us4;
typedef __attribute__((ext_vector_type(8))) unsigned short us8;

__device__ __forceinline__ unsigned short f2bf(float f) {
    unsigned u = __builtin_bit_cast(unsigned, f);
    u += 0x7fffu + ((u >> 16) & 1u);          // RNE
    return (unsigned short)(u >> 16);
}

__device__ __forceinline__ void async16(const unsigned short* g, unsigned short* l) {
    __builtin_amdgcn_global_load_lds(
        (const __attribute__((address_space(1))) unsigned int*)g,
        (__attribute__((address_space(3))) unsigned int*)l, 16, 0, 0);
}

#define MFMA_(d, va, vb) d = __builtin_amdgcn_mfma_f32_16x16x32_bf16(va, vb, d, 0, 0, 0)

// ---------------- sync-state zero (every launch, before mega) ----------------
__global__ void zero_sync(unsigned* s, int n) {
    for (int i = threadIdx.x; i < n; i += 256) s[i] = 0;
}

// ---------------- prep: x0 f32->bf16 + three W transposes ----------------
__global__ void prep(const float* __restrict__ x0, unsigned short* __restrict__ P0, long n4,
                     const float* __restrict__ W1, const float* __restrict__ W2,
                     const float* __restrict__ W3, unsigned short* __restrict__ WT1,
                     unsigned short* __restrict__ WT2, unsigned short* __restrict__ WT3,
                     int F) {
    long i = (long)blockIdx.x * blockDim.x + threadIdx.x;
    long stride = (long)gridDim.x * blockDim.x;
    for (long k = i; k < n4; k += stride) {
        float4 v = ((const float4*)x0)[k];
        us4 o;
        o.x = f2bf(v.x); o.y = f2bf(v.y); o.z = f2bf(v.z); o.w = f2bf(v.w);
        ((us4*)P0)[k] = o;
    }
    const long FF = (long)F * F;
    for (long k = i; k < 3 * FF; k += stride) {
        int w = (int)(k / FF);
        long idx = k % FF;
        int r = (int)(idx % F);
        int c = (int)(idx / F);
        const float* W = (w == 0) ? W1 : (w == 1) ? W2 : W3;
        unsigned short* WT = (w == 0) ? WT1 : (w == 1) ? WT2 : WT3;
        WT[idx] = f2bf(W[(size_t)r * F + c]);
    }
}

// ---------------- block-uniform flag wait / grid barrier ----------------
__device__ __forceinline__ void waitge(unsigned* p, unsigned tgt, int t) {
    if (t == 0) {
        while (__hip_atomic_load(p, __ATOMIC_ACQUIRE, __HIP_MEMORY_SCOPE_AGENT) < tgt)
            __builtin_amdgcn_s_sleep(2);
    }
    __syncthreads();
    __builtin_amdgcn_sched_barrier(0);
}

__device__ __forceinline__ void gbar(unsigned* slot, unsigned nb, int t) {
    __syncthreads();
    if (t == 0) {
        __hip_atomic_fetch_add(slot, 1u, __ATOMIC_ACQ_REL, __HIP_MEMORY_SCOPE_AGENT);
        while (__hip_atomic_load(slot, __ATOMIC_ACQUIRE, __HIP_MEMORY_SCOPE_AGENT) < nb)
            __builtin_amdgcn_s_sleep(2);
    }
    __syncthreads();
    __builtin_amdgcn_sched_barrier(0);
}

// ---------------- GEMM core: C = A @ B (B given transposed) ----------------
// lgTN: log2 of N-tiles (G1:2, G2:1); bpb==8 for both shapes (bat=lb>>3).
// wTf: per-producer-tile flags to await (G2); wCvt: per-batch cvt counters;
// sTf: flag array to signal own tile done (G1).
__device__ __forceinline__ void gemm_core(
    unsigned short* Lraw,
    const unsigned short* __restrict__ A, const unsigned short* __restrict__ BT,
    void* __restrict__ Cout, const float* __restrict__ bias,
    int N, int K, int lgTN, long sA, long sBT, long sC,
    bool relu, bool outf32,
    unsigned* wTf, unsigned* wCvt, unsigned* sTf, int lb)
{
    const int t    = threadIdx.x;
    const int lane = t & 63;
    const int wv   = t >> 6;
    const int wm   = wv >> 2;
    const int wn   = wv & 3;
    const int fr   = lane & 15;
    const int fk   = (lane >> 4) * 8;
    const int r4   = (lane >> 4) * 4;

    const int bat = lb >> 3;
    const int tt  = lb & 7;
    const int m0  = (tt >> lgTN) << 8;
    const int n0  = (tt & ((1 << lgTN) - 1)) << 8;
    const int nfeat = n0 >> 8;

    const unsigned short* Ab = A  + (size_t)bat * sA  + (size_t)m0 * K;
    const unsigned short* Bb = BT + (size_t)bat * sBT + (size_t)n0 * K;

    int srow[2], scol[2], lo[2];
#pragma unroll
    for (int r = 0; r < 2; ++r) {
        int c   = r * 512 + t;
        srow[r] = c >> 3;
        scol[r] = ((c & 7) * 8) ^ ((srow[r] & 7) << 3);
        lo[r]   = c * 8;
    }

    auto stageA = [&](int kt, int h) {
        unsigned short* base = Lraw + (kt & 1) * 16384;
#pragma unroll
        for (int r = 0; r < 2; ++r)
            async16(Ab + (size_t)(h * 128 + srow[r]) * K + kt * 64 + scol[r],
                    base + h * 8192 + lo[r]);
    };
    auto stageB = [&](int kt, int h) {
        unsigned short* base = Lraw + 32768 + (kt & 1) * 16384;
#pragma unroll
        for (int r = 0; r < 2; ++r)
            async16(Bb + (size_t)(h * 128 + srow[r]) * K + kt * 64 + scol[r],
                    base + h * 8192 + lo[r]);
    };
    auto rdA = [&](int buf, int mf, int kkj) -> bf16x8s {
        int row = wm * 128 + mf * 16 + fr;
        int e   = (kkj * 32 + fk) ^ ((row & 7) << 3);
        return *(const bf16x8s*)&Lraw[buf * 16384 + row * 64 + e];
    };
    auto rdB = [&](int buf, int nf, int kkj) -> bf16x8s {
        int row = wn * 64 + nf * 16 + fr;
        int e   = (kkj * 32 + fk) ^ ((row & 7) << 3);
        return *(const bf16x8s*)&Lraw[32768 + buf * 16384 + row * 64 + e];
    };

    const int nt = K >> 6;

    f32x4 acc[8][4];
#pragma unroll
    for (int i = 0; i < 8; ++i)
#pragma unroll
        for (int j = 0; j < 4; ++j) acc[i][j] = f32x4{0.f, 0.f, 0.f, 0.f};

    bf16x8s aP[4], aB[4], aC[4], bX[4], bY[4];

    // deps for K-tile 0 (node-tile 0)
    if (wCvt) waitge(&wCvt[bat], 8, t);
    if (wTf)  waitge(&wTf[bat * 8 + nfeat * 4 + 0], 1, t);

    stageA(0, 0); stageB(0, 0); stageA(0, 1); stageB(0, 1);
    asm volatile("s_waitcnt vmcnt(0)" ::: "memory");
    __builtin_amdgcn_s_barrier();
#pragma unroll
    for (int m = 0; m < 4; ++m) aP[m] = rdA(0, m, 0);
#pragma unroll
    for (int n = 0; n < 4; ++n) bX[n] = rdB(0, n, 0);

    for (int it = 0; it < nt; ++it) {
        const int cur  = it & 1;
        const int nxt  = cur ^ 1;
        const bool more = (it + 1 < nt);

        // flag for next K-tile's node-tile (G2 only; changes every 4 tiles)
        if (wTf && more && (((it + 1) & 3) == 0))
            waitge(&wTf[bat * 8 + nfeat * 4 + ((it + 1) >> 2)], 1, t);

        // ph0: MFMA m0-3 x k0; read A(m4-7,k0); stage h0 of t+1
        __builtin_amdgcn_s_barrier();
#pragma unroll
        for (int m = 0; m < 4; ++m) aB[m] = rdA(cur, m + 4, 0);
        if (more) { stageA(it + 1, 0); stageB(it + 1, 0); }
        __builtin_amdgcn_s_setprio(1);
#pragma unroll
        for (int m = 0; m < 4; ++m)
#pragma unroll
            for (int n = 0; n < 4; ++n) MFMA_(acc[m][n], aP[m], bX[n]);
        __builtin_amdgcn_s_setprio(0);

        // ph1: MFMA m4-7 x k0; read A(m0-3,k1)+B(k1); stage h1 of t+1
        __builtin_amdgcn_s_barrier();
#pragma unroll
        for (int m = 0; m < 4; ++m) aC[m] = rdA(cur, m, 1);
#pragma unroll
        for (int n = 0; n < 4; ++n) bY[n] = rdB(cur, n, 1);
        if (more) { stageA(it + 1, 1); stageB(it + 1, 1); }
        __builtin_amdgcn_s_setprio(1);
#pragma unroll
        for (int m = 0; m < 4; ++m)
#pragma unroll
            for (int n = 0; n < 4; ++n) MFMA_(acc[m + 4][n], aB[m], bX[n]);
        __builtin_amdgcn_s_setprio(0);

        // ph2: MFMA m0-3 x k1; read A(m4-7,k1)
        __builtin_amdgcn_s_barrier();
#pragma unroll
        for (int m = 0; m < 4; ++m) aB[m] = rdA(cur, m + 4, 1);
        __builtin_amdgcn_s_setprio(1);
#pragma unroll
        for (int m = 0; m < 4; ++m)
#pragma unroll
            for (int n = 0; n < 4; ++n) MFMA_(acc[m][n], aC[m], bY[n]);
        __builtin_amdgcn_s_setprio(0);

        // ph3: t+1 visibility; read next (m0-3,k0)+B(k0); MFMA m4-7 x k1
        if (more) {
            asm volatile("s_waitcnt vmcnt(0)" ::: "memory");
            __builtin_amdgcn_s_barrier();
#pragma unroll
            for (int m = 0; m < 4; ++m) aP[m] = rdA(nxt, m, 0);
#pragma unroll
            for (int n = 0; n < 4; ++n) bX[n] = rdB(nxt, n, 0);
        }
        __builtin_amdgcn_s_setprio(1);
#pragma unroll
        for (int m = 0; m < 4; ++m)
#pragma unroll
            for (int n = 0; n < 4; ++n) MFMA_(acc[m + 4][n], aB[m], bY[n]);
        __builtin_amdgcn_s_setprio(0);
    }

    __syncthreads();   // K-loop LDS reads done before epilogue reuses LDS

    // ---------------- epilogue: row-major C [M][N] ----------------
    const int R0 = m0 + wm * 128;
    const int C0 = n0 + wn * 64;
    float bv[4];
#pragma unroll
    for (int j = 0; j < 4; ++j)
        bv[j] = bias ? bias[C0 + j * 16 + fr] : 0.f;

    if (outf32) {
        float* Cb = (float*)Cout + (size_t)bat * sC;
#pragma unroll
        for (int j = 0; j < 4; ++j)
#pragma unroll
            for (int i = 0; i < 8; ++i)
#pragma unroll
                for (int e = 0; e < 4; ++e) {
                    float v = acc[i][j][e] + bv[j];
                    if (relu) v = fmaxf(v, 0.f);
                    Cb[(size_t)(R0 + i * 16 + r4 + e) * N + C0 + j * 16 + fr] = v;
                }
    } else {
        unsigned short* sl = Lraw + wv * 8192;
#pragma unroll
        for (int i = 0; i < 8; ++i)
#pragma unroll
            for (int j = 0; j < 4; ++j)
#pragma unroll
                for (int e = 0; e < 4; ++e) {
                    float v = acc[i][j][e] + bv[j];
                    if (relu) v = fmaxf(v, 0.f);
                    const int row = i * 16 + r4 + e;
                    const int col = j * 16 + fr;
                    sl[row * 64 + (col ^ ((row & 7) << 3))] = f2bf(v);
                }
        unsigned short* Cb = (unsigned short*)Cout + (size_t)bat * sC;
#pragma unroll
        for (int rr = 0; rr < 16; ++rr) {
            const int row = rr * 8 + (lane >> 3);
            const int k8  = lane & 7;
            us8 v = *(const us8*)&sl[row * 64 + ((k8 ^ (row & 7)) << 3)];
            *(us8*)&Cb[(size_t)(R0 + row) * N + C0 + k8 * 8] = v;
        }
    }

    __syncthreads();   // all stores + LDS reads done (vmcnt drained pre-barrier)
    if (sTf && t == 0)
        __hip_atomic_fetch_add(&sTf[lb], 1u, __ATOMIC_RELEASE, __HIP_MEMORY_SCOPE_AGENT);
}

// ---------------- persistent mega-kernel ----------------
__global__ __launch_bounds__(512, 2)
void mega(const float* __restrict__ adjf,
          unsigned short* __restrict__ adjb,
          unsigned short* __restrict__ P0, unsigned short* __restrict__ P1,
          unsigned short* __restrict__ PT,
          const unsigned short* __restrict__ WT1, const unsigned short* __restrict__ WT2,
          const unsigned short* __restrict__ WT3,
          const float* __restrict__ b1, const float* __restrict__ b2,
          const float* __restrict__ b3,
          float* __restrict__ dout,
          unsigned* __restrict__ sync)
{
    __shared__ unsigned short Lraw[65536];

    const int t   = threadIdx.x;
    const int cpx = 32;                                    // grid 256, 8 XCDs
    const int lb  = ((int)blockIdx.x & 7) * cpx + ((int)blockIdx.x >> 3);

    unsigned* slots  = sync;            // [0,16)
    unsigned* tflags = sync + 16;       // 3 x 256
    unsigned* cvtcnt = sync + 16 + 768; // 32

    const long sX  = 1024L * 512;
    const long sAd = 1024L * 1024;

    const unsigned short* Wt[3]  = {WT1, WT2, WT3};
    const unsigned short* Xin[3] = {P0, P1, P0};
    const float* bb[3]           = {b1, b2, b3};

    for (int l = 0; l < 3; ++l) {
        // G1: PT = WT_l @ Xin_l^T   (M=512, N=1024, K=512, lgTN=2)
        gemm_core(Lraw, Wt[l], Xin[l], PT, nullptr,
                  1024, 512, 2, 0, sX, sX,
                  false, false, nullptr, nullptr, &tflags[l * 256], lb);

        if (l == 0) {
            // adj f32->bf16 slice: batch lb>>3, rows [s*128, s*128+128)
            const int bc = lb >> 3, s = lb & 7;
            const float4* src = (const float4*)adjf + ((size_t)bc * 262144 + (size_t)s * 32768);
            us4* dst = (us4*)adjb + ((size_t)bc * 262144 + (size_t)s * 32768);
            for (int i = t; i < 32768; i += 512) {
                float4 v = src[i];
                us4 o;
                o.x = f2bf(v.x); o.y = f2bf(v.y); o.z = f2bf(v.z); o.w = f2bf(v.w);
                dst[i] = o;
            }
            __syncthreads();
            if (t == 0)
                __hip_atomic_fetch_add(&cvtcnt[bc], 1u, __ATOMIC_RELEASE, __HIP_MEMORY_SCOPE_AGENT);
        }

        // G2: Xout = adj @ PT^T (+bias, relu; layer 3 -> f32 d_out)
        void* outp = (l == 0) ? (void*)P1 : (l == 1) ? (void*)P0 : (void*)dout;
        gemm_core(Lraw, adjb, PT, outp, bb[l],
                  512, 1024, 1, sAd, sX, sX,
                  /*relu=*/(l < 2), /*outf32=*/(l == 2),
                  &tflags[l * 256], (l == 0) ? cvtcnt : nullptr, nullptr, lb);

        if (l < 2) gbar(&slots[l], 256, t);   // WAR: next G1 rewrites PT
    }
}

extern "C" void kernel_launch(void* const* d_in, const int* in_sizes, int n_in,
                              void* d_out, int out_size, void* d_ws, size_t ws_size,
                              hipStream_t stream) {
    constexpr int B = 32, N = 1024, F = 512;

    const float* x0f  = (const float*)d_in[0];
    const float* adjf = (const float*)d_in[1];
    const float* W1 = (const float*)d_in[2];
    const float* b1 = (const float*)d_in[3];
    const float* W2 = (const float*)d_in[4];
    const float* b2 = (const float*)d_in[5];
    const float* W3 = (const float*)d_in[6];
    const float* b3 = (const float*)d_in[7];

    unsigned short* ws   = (unsigned short*)d_ws;
    unsigned short* adjb = ws;                           // B*N*N
    unsigned short* P0   = adjb + (size_t)B * N * N;
    unsigned short* P1   = P0 + (size_t)B * N * F;
    unsigned short* PT   = P1 + (size_t)B * N * F;
    unsigned short* WT1  = PT + (size_t)B * N * F;
    unsigned short* WT2  = WT1 + (size_t)F * F;
    unsigned short* WT3  = WT2 + (size_t)F * F;
    unsigned* sync       = (unsigned*)(WT3 + (size_t)F * F);
    constexpr int SYNC_WORDS = 16 + 3 * 256 + 32;

    zero_sync<<<1, 256, 0, stream>>>(sync, SYNC_WORDS);
    prep<<<2048, 256, 0, stream>>>(x0f, P0, (long)B * N * F / 4,
                                   W1, W2, W3, WT1, WT2, WT3, F);
    mega<<<256, 512, 0, stream>>>(adjf, adjb, P0, P1, PT, WT1, WT2, WT3,
                                  b1, b2, b3, (float*)d_out, sync);
}

// Round 6
// 264.261 us; speedup vs baseline: 2.7915x; 2.7915x over previous
//
#include <hip/hip_runtime.h>
#include <hip/hip_bf16.h>

// GCN: 3 x [ relu(A @ (X @ W) + b) ]  (no relu layer 3), fp32 I/O, bf16 MFMA.
// All-row-major chain (separate dispatches; R3 structure, known-good):
//   G1: T  = W^T @ X^T : gemm(A=WT [F][F], BT=X [N][F]) -> T [F][N]
//   G2: X' = adj @ T^T : gemm(A=adj [N][N], BT=T [F][N]) -> X' [N][F] (+b, relu)
// NEW: adj f32->bf16 convert runs as a per-block TAIL of G1 layer 1 (the one
// GEMM not touching adjb). Program order + dispatch boundary => no flags, no
// atomics. Early-finishing GEMM blocks stream-convert while others compute.
// Core: 256x256 tile, BK=64, 8 waves (2Mx4N), dbuf LDS, read-ahead 4-phase
// pipeline, XOR-swizzled LDS, setprio, XCD-chunked swizzle, LDS-bounced
// us8 coalesced epilogue.

typedef __attribute__((ext_vector_type(8))) short bf16x8s;
typedef __attribute__((ext_vector_type(4))) float f32x4;
typedef __attribute__((ext_vector_type(4))) unsigned short us4;
typedef __attribute__((ext_vector_type(8))) unsigned short us8;

__device__ __forceinline__ unsigned short f2bf(float f) {
    unsigned u = __builtin_bit_cast(unsigned, f);
    u += 0x7fffu + ((u >> 16) & 1u);          // RNE
    return (unsigned short)(u >> 16);
}

__device__ __forceinline__ void async16(const unsigned short* g, unsigned short* l) {
    __builtin_amdgcn_global_load_lds(
        (const __attribute__((address_space(1))) unsigned int*)g,
        (__attribute__((address_space(3))) unsigned int*)l, 16, 0, 0);
}

#define MFMA_(d, va, vb) d = __builtin_amdgcn_mfma_f32_16x16x32_bf16(va, vb, d, 0, 0, 0)

// ---------------- prep: x0 f32->bf16 + three W transposes ----------------
__global__ void prep(const float* __restrict__ x0, unsigned short* __restrict__ P0, long n4,
                     const float* __restrict__ W1, const float* __restrict__ W2,
                     const float* __restrict__ W3, unsigned short* __restrict__ WT1,
                     unsigned short* __restrict__ WT2, unsigned short* __restrict__ WT3,
                     int F) {
    long i = (long)blockIdx.x * blockDim.x + threadIdx.x;
    long stride = (long)gridDim.x * blockDim.x;
    for (long k = i; k < n4; k += stride) {
        float4 v = ((const float4*)x0)[k];
        us4 o;
        o.x = f2bf(v.x); o.y = f2bf(v.y); o.z = f2bf(v.z); o.w = f2bf(v.w);
        ((us4*)P0)[k] = o;
    }
    const long FF = (long)F * F;
    for (long k = i; k < 3 * FF; k += stride) {
        int w = (int)(k / FF);
        long idx = k % FF;
        int r = (int)(idx % F);
        int c = (int)(idx / F);
        const float* W = (w == 0) ? W1 : (w == 1) ? W2 : W3;
        unsigned short* WT = (w == 0) ? WT1 : (w == 1) ? WT2 : WT3;
        WT[idx] = f2bf(W[(size_t)r * F + c]);
    }
}

// ---------------- batched GEMM C = A @ B,  B given transposed ----------------
// A : bf16 [bat][M][K] (sA==0 -> shared); BT : bf16 [bat][N][K]
// Out row-major [bat][M][N]; CVTTAIL: after epilogue, convert this block's
// adj slice f32->bf16 (no sync needed; next dispatch consumes adjb).
template<bool RELU, bool OUT_F32, bool CVTTAIL>
__global__ __launch_bounds__(512, 2)
void gemm256(const unsigned short* __restrict__ A,
             const unsigned short* __restrict__ BT,
             void* __restrict__ Cout,
             const float* __restrict__ bias,
             int M, int N, int K,
             long sA, long sBT, long sC,
             const float* __restrict__ adjf,
             unsigned short* __restrict__ adjb)
{
    __shared__ unsigned short Lraw[65536];     // 128 KiB: A dbuf [0,32K) | B dbuf [32K,64K)

    const int t    = threadIdx.x;
    const int lane = t & 63;
    const int wv   = t >> 6;
    const int wm   = wv >> 2;          // 0..1  -> 128-row half
    const int wn   = wv & 3;           // 0..3  -> 64-col strip
    const int fr   = lane & 15;
    const int fk   = (lane >> 4) * 8;
    const int r4   = (lane >> 4) * 4;

    const int tilesN = N >> 8;
    const int bpb    = (M >> 8) * tilesN;
    const int cpx = gridDim.x >> 3;    // grid divisible by 8 -> bijective
    const int lb  = (blockIdx.x & 7) * cpx + (blockIdx.x >> 3);
    const int bat = lb / bpb;
    const int tt  = lb % bpb;
    const int m0  = (tt / tilesN) << 8;
    const int n0  = (tt % tilesN) << 8;

    const unsigned short* Ab = A  + (size_t)bat * sA  + (size_t)m0 * K;
    const unsigned short* Bb = BT + (size_t)bat * sBT + (size_t)n0 * K;

    // staging: chunk c = r*512+t -> LDS elems [c*8, c*8+8) of a 128-row half-tile
    int srow[2], scol[2], lo[2];
#pragma unroll
    for (int r = 0; r < 2; ++r) {
        int c   = r * 512 + t;
        srow[r] = c >> 3;
        scol[r] = ((c & 7) * 8) ^ ((srow[r] & 7) << 3);
        lo[r]   = c * 8;
    }

    auto stageA = [&](int kt, int h) {
        unsigned short* base = Lraw + (kt & 1) * 16384;
#pragma unroll
        for (int r = 0; r < 2; ++r)
            async16(Ab + (size_t)(h * 128 + srow[r]) * K + kt * 64 + scol[r],
                    base + h * 8192 + lo[r]);
    };
    auto stageB = [&](int kt, int h) {
        unsigned short* base = Lraw + 32768 + (kt & 1) * 16384;
#pragma unroll
        for (int r = 0; r < 2; ++r)
            async16(Bb + (size_t)(h * 128 + srow[r]) * K + kt * 64 + scol[r],
                    base + h * 8192 + lo[r]);
    };
    auto rdA = [&](int buf, int mf, int kkj) -> bf16x8s {
        int row = wm * 128 + mf * 16 + fr;
        int e   = (kkj * 32 + fk) ^ ((row & 7) << 3);
        return *(const bf16x8s*)&Lraw[buf * 16384 + row * 64 + e];
    };
    auto rdB = [&](int buf, int nf, int kkj) -> bf16x8s {
        int row = wn * 64 + nf * 16 + fr;
        int e   = (kkj * 32 + fk) ^ ((row & 7) << 3);
        return *(const bf16x8s*)&Lraw[32768 + buf * 16384 + row * 64 + e];
    };

    const int nt = K >> 6;

    f32x4 acc[8][4];
#pragma unroll
    for (int i = 0; i < 8; ++i)
#pragma unroll
        for (int j = 0; j < 4; ++j) acc[i][j] = f32x4{0.f, 0.f, 0.f, 0.f};

    bf16x8s aP[4], aB[4], aC[4], bX[4], bY[4];

    // ---- prologue: stage tile0; read (m0-3,k0) + B(k0) ----
    stageA(0, 0); stageB(0, 0); stageA(0, 1); stageB(0, 1);
    asm volatile("s_waitcnt vmcnt(0)" ::: "memory");
    __builtin_amdgcn_s_barrier();
#pragma unroll
    for (int m = 0; m < 4; ++m) aP[m] = rdA(0, m, 0);
#pragma unroll
    for (int n = 0; n < 4; ++n) bX[n] = rdB(0, n, 0);

    for (int it = 0; it < nt; ++it) {
        const int cur  = it & 1;
        const int nxt  = cur ^ 1;
        const bool more = (it + 1 < nt);

        // ph0: MFMA m0-3 x k0; read A(m4-7,k0); stage h0 of t+1
        __builtin_amdgcn_s_barrier();
#pragma unroll
        for (int m = 0; m < 4; ++m) aB[m] = rdA(cur, m + 4, 0);
        if (more) { stageA(it + 1, 0); stageB(it + 1, 0); }
        __builtin_amdgcn_s_setprio(1);
#pragma unroll
        for (int m = 0; m < 4; ++m)
#pragma unroll
            for (int n = 0; n < 4; ++n) MFMA_(acc[m][n], aP[m], bX[n]);
        __builtin_amdgcn_s_setprio(0);

        // ph1: MFMA m4-7 x k0; read A(m0-3,k1)+B(k1); stage h1 of t+1
        __builtin_amdgcn_s_barrier();
#pragma unroll
        for (int m = 0; m < 4; ++m) aC[m] = rdA(cur, m, 1);
#pragma unroll
        for (int n = 0; n < 4; ++n) bY[n] = rdB(cur, n, 1);
        if (more) { stageA(it + 1, 1); stageB(it + 1, 1); }
        __builtin_amdgcn_s_setprio(1);
#pragma unroll
        for (int m = 0; m < 4; ++m)
#pragma unroll
            for (int n = 0; n < 4; ++n) MFMA_(acc[m + 4][n], aB[m], bX[n]);
        __builtin_amdgcn_s_setprio(0);

        // ph2: MFMA m0-3 x k1; read A(m4-7,k1)
        __builtin_amdgcn_s_barrier();
#pragma unroll
        for (int m = 0; m < 4; ++m) aB[m] = rdA(cur, m + 4, 1);
        __builtin_amdgcn_s_setprio(1);
#pragma unroll
        for (int m = 0; m < 4; ++m)
#pragma unroll
            for (int n = 0; n < 4; ++n) MFMA_(acc[m][n], aC[m], bY[n]);
        __builtin_amdgcn_s_setprio(0);

        // ph3: t+1 visibility; read next (m0-3,k0)+B(k0); MFMA m4-7 x k1
        if (more) {
            asm volatile("s_waitcnt vmcnt(0)" ::: "memory");
            __builtin_amdgcn_s_barrier();
#pragma unroll
            for (int m = 0; m < 4; ++m) aP[m] = rdA(nxt, m, 0);
#pragma unroll
            for (int n = 0; n < 4; ++n) bX[n] = rdB(nxt, n, 0);
        }
        __builtin_amdgcn_s_setprio(1);
#pragma unroll
        for (int m = 0; m < 4; ++m)
#pragma unroll
            for (int n = 0; n < 4; ++n) MFMA_(acc[m + 4][n], aB[m], bY[n]);
        __builtin_amdgcn_s_setprio(0);
    }

    __syncthreads();   // K-loop LDS reads done before epilogue reuses LDS

    // ---------------- epilogue: row-major C [M][N] ----------------
    const int R0 = m0 + wm * 128;
    const int C0 = n0 + wn * 64;
    float bv[4];
#pragma unroll
    for (int j = 0; j < 4; ++j)
        bv[j] = bias ? bias[C0 + j * 16 + fr] : 0.f;

    if (OUT_F32) {
        float* Cb = (float*)Cout + (size_t)bat * sC;
#pragma unroll
        for (int j = 0; j < 4; ++j)
#pragma unroll
            for (int i = 0; i < 8; ++i)
#pragma unroll
                for (int e = 0; e < 4; ++e) {
                    float v = acc[i][j][e] + bv[j];
                    if (RELU) v = fmaxf(v, 0.f);
                    Cb[(size_t)(R0 + i * 16 + r4 + e) * N + C0 + j * 16 + fr] = v;
                }
    } else {
        // LDS bounce -> us8 coalesced stores
        unsigned short* sl = Lraw + wv * 8192;
#pragma unroll
        for (int i = 0; i < 8; ++i)
#pragma unroll
            for (int j = 0; j < 4; ++j)
#pragma unroll
                for (int e = 0; e < 4; ++e) {
                    float v = acc[i][j][e] + bv[j];
                    if (RELU) v = fmaxf(v, 0.f);
                    const int row = i * 16 + r4 + e;
                    const int col = j * 16 + fr;
                    sl[row * 64 + (col ^ ((row & 7) << 3))] = f2bf(v);
                }
        unsigned short* Cb = (unsigned short*)Cout + (size_t)bat * sC;
#pragma unroll
        for (int rr = 0; rr < 16; ++rr) {
            const int row = rr * 8 + (lane >> 3);
            const int k8  = lane & 7;
            us8 v = *(const us8*)&sl[row * 64 + ((k8 ^ (row & 7)) << 3)];
            *(us8*)&Cb[(size_t)(R0 + row) * N + C0 + k8 * 8] = v;
        }
    }

    // ---------------- CVT tail: adj slice f32->bf16 (layer-1 G1 only) --------
    // Block lb owns batch lb>>3, rows [(lb&7)*128, +128). Next dispatch (G2_1)
    // consumes adjb; the dispatch boundary is the fence — no flags needed.
    if constexpr (CVTTAIL) {
        const int bc = lb >> 3, s = lb & 7;
        const float4* src = (const float4*)adjf + ((size_t)bc * 262144 + (size_t)s * 32768);
        us4* dst = (us4*)adjb + ((size_t)bc * 262144 + (size_t)s * 32768);
        for (int i = t; i < 32768; i += 512) {
            float4 v = src[i];
            us4 o;
            o.x = f2bf(v.x); o.y = f2bf(v.y); o.z = f2bf(v.z); o.w = f2bf(v.w);
            dst[i] = o;
        }
    }
}

extern "C" void kernel_launch(void* const* d_in, const int* in_sizes, int n_in,
                              void* d_out, int out_size, void* d_ws, size_t ws_size,
                              hipStream_t stream) {
    constexpr int B = 32, N = 1024, F = 512;

    const float* x0f  = (const float*)d_in[0];
    const float* adjf = (const float*)d_in[1];
    const float* W1 = (const float*)d_in[2];
    const float* b1 = (const float*)d_in[3];
    const float* W2 = (const float*)d_in[4];
    const float* b2 = (const float*)d_in[5];
    const float* W3 = (const float*)d_in[6];
    const float* b3 = (const float*)d_in[7];

    unsigned short* ws   = (unsigned short*)d_ws;
    unsigned short* adjb = ws;                           // B*N*N
    unsigned short* P0   = adjb + (size_t)B * N * N;     // B*N*F  (X buffers)
    unsigned short* P1   = P0 + (size_t)B * N * F;
    unsigned short* PT   = P1 + (size_t)B * N * F;       // B*F*N  (T buffer)
    unsigned short* WT1  = PT + (size_t)B * N * F;
    unsigned short* WT2  = WT1 + (size_t)F * F;
    unsigned short* WT3  = WT2 + (size_t)F * F;

    prep<<<2048, 256, 0, stream>>>(x0f, P0, (long)B * N * F / 4,
                                   W1, W2, W3, WT1, WT2, WT3, F);

    const int grid = 256;                 // both GEMM shapes: 32 bat x 8 tiles
    const long sX = (long)N * F;
    const long sAd = (long)N * N;

    // layer 1 (G1 carries the adj-convert tail)
    gemm256<false, false, true ><<<grid, 512, 0, stream>>>(WT1,  P0, PT, nullptr, F, N, F, 0,  sX, sX, adjf, adjb);
    gemm256<true,  false, false><<<grid, 512, 0, stream>>>(adjb, PT, P1, b1,      N, F, N, sAd, sX, sX, nullptr, nullptr);
    // layer 2
    gemm256<false, false, false><<<grid, 512, 0, stream>>>(WT2,  P1, PT, nullptr, F, N, F, 0,  sX, sX, nullptr, nullptr);
    gemm256<true,  false, false><<<grid, 512, 0, stream>>>(adjb, PT, P0, b2,      N, F, N, sAd, sX, sX, nullptr, nullptr);
    // layer 3 (fp32 out, no relu)
    gemm256<false, false, false><<<grid, 512, 0, stream>>>(WT3,  P0, PT, nullptr, F, N, F, 0,  sX, sX, nullptr, nullptr);
    gemm256<false, true,  false><<<grid, 512, 0, stream>>>(adjb, PT, (float*)d_out, b3, N, F, N, sAd, sX, sX, nullptr, nullptr);
}